// Round 1
// baseline (902.152 us; speedup 1.0000x reference)
//
#include <hip/hip_runtime.h>
#include <hip/hip_bf16.h>
#include <math.h>

// ---------------------------------------------------------------------------
// ActivityRecognitionGCN: 3x GCNConv(+ReLU) -> mean pool per graph -> MLP head
// N=100000 nodes, E=3.2M edges, G=1024 graphs, F: 128->64->64->32
// Strategy: build CSR-by-dst once (deg/dinv reused by all layers), then each
// layer = dense GEMM (vector fp32, W in LDS) + gather-aggregate (wave/node).
// ---------------------------------------------------------------------------

__global__ void zero_int_kernel(int* __restrict__ p, int n) {
  int i = blockIdx.x * blockDim.x + threadIdx.x;
  if (i < n) p[i] = 0;
}

__global__ void count_deg_kernel(const int* __restrict__ dst, int* __restrict__ deg, int E) {
  int i = blockIdx.x * blockDim.x + threadIdx.x;
  if (i < E) atomicAdd(&deg[dst[i]], 1);
}

// Block scans 1024 elements (4/thread). Writes within-block exclusive scan,
// block totals, and dinv = (deg+1)^-0.5 (deg is in-degree; +1 = self loop).
__global__ __launch_bounds__(256) void scan_blocks_kernel(const int* __restrict__ deg,
    int* __restrict__ offs, int* __restrict__ bsum, float* __restrict__ dinv, int n) {
  __shared__ int sh[256];
  const int tid = threadIdx.x;
  const int base = blockIdx.x * 1024 + tid * 4;
  int v[4];
#pragma unroll
  for (int j = 0; j < 4; ++j) v[j] = (base + j < n) ? deg[base + j] : 0;
#pragma unroll
  for (int j = 0; j < 4; ++j)
    if (base + j < n) dinv[base + j] = 1.0f / sqrtf((float)(v[j] + 1));
  int s = v[0] + v[1] + v[2] + v[3];
  sh[tid] = s;
  __syncthreads();
  for (int d = 1; d < 256; d <<= 1) {
    int t = 0;
    if (tid >= d) t = sh[tid - d];
    __syncthreads();
    if (tid >= d) sh[tid] += t;
    __syncthreads();
  }
  int excl = sh[tid] - s;
  if (tid == 255) bsum[blockIdx.x] = sh[tid];
  int run = excl;
#pragma unroll
  for (int j = 0; j < 4; ++j) {
    if (base + j < n) offs[base + j] = run;
    run += v[j];
  }
}

__global__ __launch_bounds__(256) void scan_bsums_kernel(int* __restrict__ bsum, int nb) {
  __shared__ int sh[256];
  const int tid = threadIdx.x;
  int s = (tid < nb) ? bsum[tid] : 0;
  sh[tid] = s;
  __syncthreads();
  for (int d = 1; d < 256; d <<= 1) {
    int t = 0;
    if (tid >= d) t = sh[tid - d];
    __syncthreads();
    if (tid >= d) sh[tid] += t;
    __syncthreads();
  }
  if (tid < nb) bsum[tid] = sh[tid] - s;  // exclusive
}

__global__ void scan_finalize_kernel(int* __restrict__ offs, int* __restrict__ cursor,
    const int* __restrict__ bsum, int n, int total) {
  int i = blockIdx.x * blockDim.x + threadIdx.x;
  if (i < n) {
    int o = offs[i] + bsum[i >> 10];
    offs[i] = o;
    cursor[i] = o;
  }
  if (i == 0) offs[n] = total;
}

__global__ void fill_csr_kernel(const int* __restrict__ src, const int* __restrict__ dst,
    int* __restrict__ cursor, int* __restrict__ csr, int E) {
  int i = blockIdx.x * blockDim.x + threadIdx.x;
  if (i < E) {
    int slot = atomicAdd(&cursor[dst[i]], 1);
    csr[slot] = src[i];
  }
}

// ---------------------------------------------------------------------------
// Dense GEMM: Y[N,M] = X[N,K] @ W[K,M].  W fully staged in LDS; 32-row X tile.
// Thread layout: rt = tid&15 owns rows {rt, rt+16}; c = tid>>4 owns MC cols.
// ---------------------------------------------------------------------------
template <int K, int M>
__global__ __launch_bounds__(256) void gemm_kernel(const float* __restrict__ X,
    const float* __restrict__ W, float* __restrict__ Y, int n) {
  constexpr int RPB = 32;       // rows per block
  constexpr int XST = K + 4;    // padded LDS stride (multiple of 4 for float4)
  constexpr int MC = M / 16;    // cols per thread (4 or 2)
  __shared__ __align__(16) float Ws[K * M];
  __shared__ __align__(16) float Xs[RPB * XST];
  const int tid = threadIdx.x;
  const int row0 = blockIdx.x * RPB;
  for (int i = tid * 4; i < K * M; i += 1024)
    *reinterpret_cast<float4*>(&Ws[i]) = *reinterpret_cast<const float4*>(&W[i]);
  for (int i = tid * 4; i < RPB * K; i += 1024) {
    int r = i / K, k = i - r * K;  // K%4==0 so 4 elems stay in one row
    int gr = row0 + r;
    float4 v = make_float4(0.f, 0.f, 0.f, 0.f);
    if (gr < n) v = *reinterpret_cast<const float4*>(&X[(size_t)gr * K + k]);
    *reinterpret_cast<float4*>(&Xs[r * XST + k]) = v;
  }
  __syncthreads();
  const int rt = tid & 15;
  const int c = tid >> 4;
  float acc[2][MC];
#pragma unroll
  for (int rr = 0; rr < 2; ++rr)
#pragma unroll
    for (int j = 0; j < MC; ++j) acc[rr][j] = 0.f;
  for (int k4 = 0; k4 < K; k4 += 4) {
    float4 xv[2];
#pragma unroll
    for (int rr = 0; rr < 2; ++rr)
      xv[rr] = *reinterpret_cast<const float4*>(&Xs[(rt + 16 * rr) * XST + k4]);
    const float* xf0 = reinterpret_cast<const float*>(&xv[0]);
    const float* xf1 = reinterpret_cast<const float*>(&xv[1]);
#pragma unroll
    for (int kk = 0; kk < 4; ++kk) {
      float w[MC];
#pragma unroll
      for (int j = 0; j < MC; ++j) w[j] = Ws[(k4 + kk) * M + c * MC + j];
      float x0 = xf0[kk], x1 = xf1[kk];
#pragma unroll
      for (int j = 0; j < MC; ++j) {
        acc[0][j] += x0 * w[j];
        acc[1][j] += x1 * w[j];
      }
    }
  }
#pragma unroll
  for (int rr = 0; rr < 2; ++rr) {
    int gr = row0 + rt + 16 * rr;
    if (gr < n) {
#pragma unroll
      for (int j = 0; j < MC; ++j) Y[(size_t)gr * M + c * MC + j] = acc[rr][j];
    }
  }
}

// ---------------------------------------------------------------------------
// Gather-aggregate: out[i,f] = relu( sum_e dinv[s]*dinv[i]*h[s,f]
//                                    + dinv[i]^2*h[i,f] + bias[f] )
// F lanes per node (F=64: one wave/node, F=32: half-wave/node).
// ---------------------------------------------------------------------------
template <int F>
__global__ __launch_bounds__(256) void agg_kernel(const float* __restrict__ h,
    const int* __restrict__ offs, const int* __restrict__ csr,
    const float* __restrict__ dinv, const float* __restrict__ bias,
    float* __restrict__ out, int n) {
  constexpr int NPB = 256 / F;
  const int node = blockIdx.x * NPB + threadIdx.x / F;
  const int f = threadIdx.x % F;
  if (node >= n) return;
  const int e0 = offs[node], e1 = offs[node + 1];
  const float di = dinv[node];
  float acc = di * di * h[(size_t)node * F + f];
  int e = e0;
  for (; e + 4 <= e1; e += 4) {
    int s0 = csr[e], s1 = csr[e + 1], s2 = csr[e + 2], s3 = csr[e + 3];
    float d0 = dinv[s0], d1 = dinv[s1], d2 = dinv[s2], d3 = dinv[s3];
    float h0 = h[(size_t)s0 * F + f];
    float h1 = h[(size_t)s1 * F + f];
    float h2 = h[(size_t)s2 * F + f];
    float h3 = h[(size_t)s3 * F + f];
    acc += di * d0 * h0;
    acc += di * d1 * h1;
    acc += di * d2 * h2;
    acc += di * d3 * h3;
  }
  for (; e < e1; ++e) {
    int s = csr[e];
    acc += di * dinv[s] * h[(size_t)s * F + f];
  }
  out[(size_t)node * F + f] = fmaxf(acc + bias[f], 0.0f);
}

// batch is sorted: per-graph node range via binary search.
__global__ void graph_ranges_kernel(const int* __restrict__ batch, int* __restrict__ gstart,
                                    int n, int G) {
  int g = blockIdx.x * blockDim.x + threadIdx.x;
  if (g > G) return;
  int lo = 0, hi = n;
  while (lo < hi) {
    int mid = (lo + hi) >> 1;
    if (batch[mid] < g) lo = mid + 1; else hi = mid;
  }
  gstart[g] = lo;
}

// One wave per graph: lane = (feature, node parity). Mean over the range.
__global__ __launch_bounds__(256) void pool_kernel(const float* __restrict__ h,
    const int* __restrict__ gstart, float* __restrict__ pooled, int G) {
  int g = blockIdx.x * 4 + (threadIdx.x >> 6);
  if (g >= G) return;
  int lane = threadIdx.x & 63;
  int f = lane & 31, sub = lane >> 5;
  int s = gstart[g], e = gstart[g + 1];
  float acc = 0.f;
  for (int i = s + sub; i < e; i += 2) acc += h[(size_t)i * 32 + f];
  acc += __shfl_xor(acc, 32);
  float mean = acc / fmaxf((float)(e - s), 1.0f);
  if (sub == 0) pooled[g * 32 + f] = mean;
}

// One thread per graph: z = relu(p@Wc1+bc1); logits = z@Wc2+bc2; log_softmax.
__global__ __launch_bounds__(256) void head_kernel(const float* __restrict__ pooled,
    const float* __restrict__ Wc1, const float* __restrict__ bc1,
    const float* __restrict__ Wc2, const float* __restrict__ bc2,
    float* __restrict__ out, int G) {
  int g = blockIdx.x * blockDim.x + threadIdx.x;
  if (g >= G) return;
  float p[32];
#pragma unroll
  for (int k = 0; k < 32; ++k) p[k] = pooled[g * 32 + k];
  float z[16];
#pragma unroll
  for (int j = 0; j < 16; ++j) {
    float a = bc1[j];
#pragma unroll
    for (int k = 0; k < 32; ++k) a += p[k] * Wc1[k * 16 + j];
    z[j] = fmaxf(a, 0.f);
  }
  float lg[16];
  float m = -1e30f;
#pragma unroll
  for (int j = 0; j < 16; ++j) {
    float a = bc2[j];
#pragma unroll
    for (int k = 0; k < 16; ++k) a += z[k] * Wc2[k * 16 + j];
    lg[j] = a;
    m = fmaxf(m, a);
  }
  float ssum = 0.f;
#pragma unroll
  for (int j = 0; j < 16; ++j) ssum += expf(lg[j] - m);
  float lse = logf(ssum);
#pragma unroll
  for (int j = 0; j < 16; ++j) out[g * 16 + j] = lg[j] - m - lse;
}

extern "C" void kernel_launch(void* const* d_in, const int* in_sizes, int n_in,
                              void* d_out, int out_size, void* d_ws, size_t ws_size,
                              hipStream_t stream) {
  const float* x   = (const float*)d_in[0];
  const int*   ei  = (const int*)d_in[1];
  const int*   batch = (const int*)d_in[2];
  const float* W1 = (const float*)d_in[3];
  const float* b1 = (const float*)d_in[4];
  const float* W2 = (const float*)d_in[5];
  const float* b2 = (const float*)d_in[6];
  const float* W3 = (const float*)d_in[7];
  const float* b3 = (const float*)d_in[8];
  const float* Wc1 = (const float*)d_in[9];
  const float* bc1 = (const float*)d_in[10];
  const float* Wc2 = (const float*)d_in[11];
  const float* bc2 = (const float*)d_in[12];

  const int N = in_sizes[2];        // 100000 (batch vector length)
  const int E = in_sizes[1] / 2;    // 3200000
  const int G = out_size / 16;      // 1024
  const int* src = ei;
  const int* dst = ei + E;

  char* ws = (char*)d_ws;
  size_t off = 0;
  auto alloc = [&](size_t bytes) -> void* {
    void* p = ws + off;
    off += (bytes + 511) & ~(size_t)511;
    return p;
  };
  int*   deg    = (int*)alloc((size_t)N * 4);
  int*   offs   = (int*)alloc(((size_t)N + 1) * 4);
  int*   cursor = (int*)alloc((size_t)N * 4);
  float* dinv   = (float*)alloc((size_t)N * 4);
  int*   bsum   = (int*)alloc(1024);
  int*   gstart = (int*)alloc(((size_t)G + 1) * 4);
  int*   csr    = (int*)alloc((size_t)E * 4);
  float* bufA   = (float*)alloc((size_t)N * 64 * 4);
  float* bufB   = (float*)alloc((size_t)N * 64 * 4);
  float* pooled = (float*)alloc((size_t)G * 32 * 4);
  (void)ws_size; (void)n_in;

  const int nb = (N + 1023) / 1024;  // scan blocks (98 <= 256)

  // --- CSR build (once; reused by all 3 layers) ---
  zero_int_kernel<<<(N + 255) / 256, 256, 0, stream>>>(deg, N);
  count_deg_kernel<<<(E + 255) / 256, 256, 0, stream>>>(dst, deg, E);
  scan_blocks_kernel<<<nb, 256, 0, stream>>>(deg, offs, bsum, dinv, N);
  scan_bsums_kernel<<<1, 256, 0, stream>>>(bsum, nb);
  scan_finalize_kernel<<<(N + 255) / 256, 256, 0, stream>>>(offs, cursor, bsum, N, E);
  fill_csr_kernel<<<(E + 255) / 256, 256, 0, stream>>>(src, dst, cursor, csr, E);

  // --- layer 1: 128 -> 64 ---
  gemm_kernel<128, 64><<<(N + 31) / 32, 256, 0, stream>>>(x, W1, bufA, N);
  agg_kernel<64><<<(N + 3) / 4, 256, 0, stream>>>(bufA, offs, csr, dinv, b1, bufB, N);
  // --- layer 2: 64 -> 64 ---
  gemm_kernel<64, 64><<<(N + 31) / 32, 256, 0, stream>>>(bufB, W2, bufA, N);
  agg_kernel<64><<<(N + 3) / 4, 256, 0, stream>>>(bufA, offs, csr, dinv, b2, bufB, N);
  // --- layer 3: 64 -> 32 ---
  gemm_kernel<64, 32><<<(N + 31) / 32, 256, 0, stream>>>(bufB, W3, bufA, N);
  agg_kernel<32><<<(N + 7) / 8, 256, 0, stream>>>(bufA, offs, csr, dinv, b3, bufB, N);

  // --- pool + head ---
  graph_ranges_kernel<<<(G + 256) / 256, 256, 0, stream>>>(batch, gstart, N, G);
  pool_kernel<<<(G + 3) / 4, 256, 0, stream>>>(bufB, gstart, pooled, G);
  head_kernel<<<(G + 255) / 256, 256, 0, stream>>>(pooled, Wc1, bc1, Wc2, bc2,
                                                   (float*)d_out, G);
}

// Round 2
// 761.199 us; speedup vs baseline: 1.1852x; 1.1852x over previous
//
#include <hip/hip_runtime.h>
#include <hip/hip_bf16.h>
#include <hip/hip_fp16.h>
#include <math.h>

// ---------------------------------------------------------------------------
// ActivityRecognitionGCN: 3x GCNConv(+ReLU) -> mean pool per graph -> MLP head
// N=100000 nodes, E=3.2M edges, G=1024 graphs, F: 128->64->64->32
// R1 -> R2 changes:
//  * CSR fill was write-allocate bound (WRITE_SIZE 195MB for 12.8MB array).
//    Now: partition edges into 98 dst-range buckets (L2-coalesced writes),
//    then fill csr per bucket so scattered stores land in a ~131KB window.
//  * GEMM outputs stored fp16 -> halves the random-gather bytes in agg.
// ---------------------------------------------------------------------------

constexpr int BSHIFT = 10;        // bucket = dst >> 10
constexpr int BCAP   = 40960;     // bucket capacity (mean 32768 + ~45 sigma)

__global__ void zero_int_kernel(int* __restrict__ p, int n) {
  int i = blockIdx.x * blockDim.x + threadIdx.x;
  if (i < n) p[i] = 0;
}

__global__ void count_deg_kernel(const int* __restrict__ dst, int* __restrict__ deg, int E) {
  int i = blockIdx.x * blockDim.x + threadIdx.x;
  if (i < E) atomicAdd(&deg[dst[i]], 1);
}

// Block scans 1024 elements (4/thread). Writes within-block exclusive scan,
// block totals, and dinv = (deg+1)^-0.5 (deg is in-degree; +1 = self loop).
__global__ __launch_bounds__(256) void scan_blocks_kernel(const int* __restrict__ deg,
    int* __restrict__ offs, int* __restrict__ bsum, float* __restrict__ dinv, int n) {
  __shared__ int sh[256];
  const int tid = threadIdx.x;
  const int base = blockIdx.x * 1024 + tid * 4;
  int v[4];
#pragma unroll
  for (int j = 0; j < 4; ++j) v[j] = (base + j < n) ? deg[base + j] : 0;
#pragma unroll
  for (int j = 0; j < 4; ++j)
    if (base + j < n) dinv[base + j] = 1.0f / sqrtf((float)(v[j] + 1));
  int s = v[0] + v[1] + v[2] + v[3];
  sh[tid] = s;
  __syncthreads();
  for (int d = 1; d < 256; d <<= 1) {
    int t = 0;
    if (tid >= d) t = sh[tid - d];
    __syncthreads();
    if (tid >= d) sh[tid] += t;
    __syncthreads();
  }
  int excl = sh[tid] - s;
  if (tid == 255) bsum[blockIdx.x] = sh[tid];
  int run = excl;
#pragma unroll
  for (int j = 0; j < 4; ++j) {
    if (base + j < n) offs[base + j] = run;
    run += v[j];
  }
}

__global__ __launch_bounds__(256) void scan_bsums_kernel(int* __restrict__ bsum, int nb) {
  __shared__ int sh[256];
  const int tid = threadIdx.x;
  int s = (tid < nb) ? bsum[tid] : 0;
  sh[tid] = s;
  __syncthreads();
  for (int d = 1; d < 256; d <<= 1) {
    int t = 0;
    if (tid >= d) t = sh[tid - d];
    __syncthreads();
    if (tid >= d) sh[tid] += t;
    __syncthreads();
  }
  if (tid < nb) bsum[tid] = sh[tid] - s;  // exclusive
}

__global__ void scan_finalize_kernel(int* __restrict__ offs, int* __restrict__ cursor,
    const int* __restrict__ bsum, int n, int total) {
  int i = blockIdx.x * blockDim.x + threadIdx.x;
  if (i < n) {
    int o = offs[i] + bsum[i >> 10];
    offs[i] = o;
    cursor[i] = o;
  }
  if (i == 0) offs[n] = total;
}

// Partition edges into buckets by dst>>BSHIFT. Each block: count per-bucket in
// LDS, reserve contiguous span per bucket via one global atomic, then scatter
// packed (dst<<32|src) into the bucket's padded region. Writes per block per
// bucket are contiguous ~340B runs -> near-full-line HBM/L2 efficiency.
__global__ __launch_bounds__(256) void partition_kernel(const int* __restrict__ src,
    const int* __restrict__ dst, int* __restrict__ bucket_cnt,
    unsigned long long* __restrict__ part, int E, int nbuckets) {
  __shared__ int lcnt[128];
  __shared__ int lbase[128];
  const int tid = threadIdx.x;
  const int base = blockIdx.x * 4096;
  if (tid < nbuckets) lcnt[tid] = 0;
  __syncthreads();
  int s[16], d[16];
#pragma unroll
  for (int j = 0; j < 16; ++j) {
    int idx = base + j * 256 + tid;
    if (idx < E) {
      s[j] = src[idx];
      d[j] = dst[idx];
      atomicAdd(&lcnt[d[j] >> BSHIFT], 1);
    } else {
      d[j] = -1;
    }
  }
  __syncthreads();
  if (tid < nbuckets) {
    lbase[tid] = atomicAdd(&bucket_cnt[tid], lcnt[tid]);
    lcnt[tid] = 0;
  }
  __syncthreads();
#pragma unroll
  for (int j = 0; j < 16; ++j) {
    if (d[j] >= 0) {
      int b = d[j] >> BSHIFT;
      int pos = lbase[b] + atomicAdd(&lcnt[b], 1);
      if (pos < BCAP)
        part[(size_t)b * BCAP + pos] =
            ((unsigned long long)(unsigned)d[j] << 32) | (unsigned)s[j];
    }
  }
}

// Fill csr per bucket: all cursor atomics + csr writes land in a ~131KB
// window -> L2-resident, lines fully filled before eviction.
__global__ __launch_bounds__(256) void fill_bucket_kernel(
    const unsigned long long* __restrict__ part, const int* __restrict__ bucket_cnt,
    int* __restrict__ cursor, int* __restrict__ csr, int pbb) {
  const int b = blockIdx.x / pbb;
  const int sub = blockIdx.x - b * pbb;
  const int cnt = min(bucket_cnt[b], BCAP);
  for (int i = sub * 256 + threadIdx.x; i < cnt; i += pbb * 256) {
    unsigned long long p = part[(size_t)b * BCAP + i];
    int sv = (int)(p & 0xffffffffull);
    int dv = (int)(p >> 32);
    int slot = atomicAdd(&cursor[dv], 1);
    csr[slot] = sv;
  }
}

// ---------------------------------------------------------------------------
// Dense GEMM: Y[N,M](fp16) = X[N,K](fp32) @ W[K,M].  W staged in LDS.
// ---------------------------------------------------------------------------
template <int K, int M>
__global__ __launch_bounds__(256) void gemm_kernel(const float* __restrict__ X,
    const float* __restrict__ W, __half* __restrict__ Y, int n) {
  constexpr int RPB = 32;       // rows per block
  constexpr int XST = K + 4;    // padded LDS stride
  constexpr int MC = M / 16;    // cols per thread (4 or 2)
  __shared__ __align__(16) float Ws[K * M];
  __shared__ __align__(16) float Xs[RPB * XST];
  const int tid = threadIdx.x;
  const int row0 = blockIdx.x * RPB;
  for (int i = tid * 4; i < K * M; i += 1024)
    *reinterpret_cast<float4*>(&Ws[i]) = *reinterpret_cast<const float4*>(&W[i]);
  for (int i = tid * 4; i < RPB * K; i += 1024) {
    int r = i / K, k = i - r * K;
    int gr = row0 + r;
    float4 v = make_float4(0.f, 0.f, 0.f, 0.f);
    if (gr < n) v = *reinterpret_cast<const float4*>(&X[(size_t)gr * K + k]);
    *reinterpret_cast<float4*>(&Xs[r * XST + k]) = v;
  }
  __syncthreads();
  const int rt = tid & 15;
  const int c = tid >> 4;
  float acc[2][MC];
#pragma unroll
  for (int rr = 0; rr < 2; ++rr)
#pragma unroll
    for (int j = 0; j < MC; ++j) acc[rr][j] = 0.f;
  for (int k4 = 0; k4 < K; k4 += 4) {
    float4 xv[2];
#pragma unroll
    for (int rr = 0; rr < 2; ++rr)
      xv[rr] = *reinterpret_cast<const float4*>(&Xs[(rt + 16 * rr) * XST + k4]);
    const float* xf0 = reinterpret_cast<const float*>(&xv[0]);
    const float* xf1 = reinterpret_cast<const float*>(&xv[1]);
#pragma unroll
    for (int kk = 0; kk < 4; ++kk) {
      float w[MC];
#pragma unroll
      for (int j = 0; j < MC; ++j) w[j] = Ws[(k4 + kk) * M + c * MC + j];
      float x0 = xf0[kk], x1 = xf1[kk];
#pragma unroll
      for (int j = 0; j < MC; ++j) {
        acc[0][j] += x0 * w[j];
        acc[1][j] += x1 * w[j];
      }
    }
  }
#pragma unroll
  for (int rr = 0; rr < 2; ++rr) {
    int gr = row0 + rt + 16 * rr;
    if (gr < n) {
#pragma unroll
      for (int j = 0; j < MC; ++j)
        Y[(size_t)gr * M + c * MC + j] = __float2half(acc[rr][j]);
    }
  }
}

// ---------------------------------------------------------------------------
// Gather-aggregate: out[i,f] = relu( sum_e dinv[s]*dinv[i]*h[s,f]
//                                    + dinv[i]^2*h[i,f] + bias[f] )
// h is fp16 (halves random-gather bytes); accumulate fp32; out fp32.
// ---------------------------------------------------------------------------
template <int F>
__global__ __launch_bounds__(256) void agg_kernel(const __half* __restrict__ h,
    const int* __restrict__ offs, const int* __restrict__ csr,
    const float* __restrict__ dinv, const float* __restrict__ bias,
    float* __restrict__ out, int n) {
  constexpr int NPB = 256 / F;
  const int node = blockIdx.x * NPB + threadIdx.x / F;
  const int f = threadIdx.x % F;
  if (node >= n) return;
  const int e0 = offs[node], e1 = offs[node + 1];
  const float di = dinv[node];
  float acc = di * di * __half2float(h[(size_t)node * F + f]);
  int e = e0;
  for (; e + 4 <= e1; e += 4) {
    int s0 = csr[e], s1 = csr[e + 1], s2 = csr[e + 2], s3 = csr[e + 3];
    float d0 = dinv[s0], d1 = dinv[s1], d2 = dinv[s2], d3 = dinv[s3];
    float h0 = __half2float(h[(size_t)s0 * F + f]);
    float h1 = __half2float(h[(size_t)s1 * F + f]);
    float h2 = __half2float(h[(size_t)s2 * F + f]);
    float h3 = __half2float(h[(size_t)s3 * F + f]);
    acc += di * d0 * h0;
    acc += di * d1 * h1;
    acc += di * d2 * h2;
    acc += di * d3 * h3;
  }
  for (; e < e1; ++e) {
    int s = csr[e];
    acc += di * dinv[s] * __half2float(h[(size_t)s * F + f]);
  }
  out[(size_t)node * F + f] = fmaxf(acc + bias[f], 0.0f);
}

// batch is sorted: per-graph node range via binary search.
__global__ void graph_ranges_kernel(const int* __restrict__ batch, int* __restrict__ gstart,
                                    int n, int G) {
  int g = blockIdx.x * blockDim.x + threadIdx.x;
  if (g > G) return;
  int lo = 0, hi = n;
  while (lo < hi) {
    int mid = (lo + hi) >> 1;
    if (batch[mid] < g) lo = mid + 1; else hi = mid;
  }
  gstart[g] = lo;
}

// One wave per graph: lane = (feature, node parity). Mean over the range.
__global__ __launch_bounds__(256) void pool_kernel(const float* __restrict__ h,
    const int* __restrict__ gstart, float* __restrict__ pooled, int G) {
  int g = blockIdx.x * 4 + (threadIdx.x >> 6);
  if (g >= G) return;
  int lane = threadIdx.x & 63;
  int f = lane & 31, sub = lane >> 5;
  int s = gstart[g], e = gstart[g + 1];
  float acc = 0.f;
  for (int i = s + sub; i < e; i += 2) acc += h[(size_t)i * 32 + f];
  acc += __shfl_xor(acc, 32);
  float mean = acc / fmaxf((float)(e - s), 1.0f);
  if (sub == 0) pooled[g * 32 + f] = mean;
}

// One thread per graph: z = relu(p@Wc1+bc1); logits = z@Wc2+bc2; log_softmax.
__global__ __launch_bounds__(256) void head_kernel(const float* __restrict__ pooled,
    const float* __restrict__ Wc1, const float* __restrict__ bc1,
    const float* __restrict__ Wc2, const float* __restrict__ bc2,
    float* __restrict__ out, int G) {
  int g = blockIdx.x * blockDim.x + threadIdx.x;
  if (g >= G) return;
  float p[32];
#pragma unroll
  for (int k = 0; k < 32; ++k) p[k] = pooled[g * 32 + k];
  float z[16];
#pragma unroll
  for (int j = 0; j < 16; ++j) {
    float a = bc1[j];
#pragma unroll
    for (int k = 0; k < 32; ++k) a += p[k] * Wc1[k * 16 + j];
    z[j] = fmaxf(a, 0.f);
  }
  float lg[16];
  float m = -1e30f;
#pragma unroll
  for (int j = 0; j < 16; ++j) {
    float a = bc2[j];
#pragma unroll
    for (int k = 0; k < 16; ++k) a += z[k] * Wc2[k * 16 + j];
    lg[j] = a;
    m = fmaxf(m, a);
  }
  float ssum = 0.f;
#pragma unroll
  for (int j = 0; j < 16; ++j) ssum += expf(lg[j] - m);
  float lse = logf(ssum);
#pragma unroll
  for (int j = 0; j < 16; ++j) out[g * 16 + j] = lg[j] - m - lse;
}

extern "C" void kernel_launch(void* const* d_in, const int* in_sizes, int n_in,
                              void* d_out, int out_size, void* d_ws, size_t ws_size,
                              hipStream_t stream) {
  const float* x   = (const float*)d_in[0];
  const int*   ei  = (const int*)d_in[1];
  const int*   batch = (const int*)d_in[2];
  const float* W1 = (const float*)d_in[3];
  const float* b1 = (const float*)d_in[4];
  const float* W2 = (const float*)d_in[5];
  const float* b2 = (const float*)d_in[6];
  const float* W3 = (const float*)d_in[7];
  const float* b3 = (const float*)d_in[8];
  const float* Wc1 = (const float*)d_in[9];
  const float* bc1 = (const float*)d_in[10];
  const float* Wc2 = (const float*)d_in[11];
  const float* bc2 = (const float*)d_in[12];

  const int N = in_sizes[2];        // 100000
  const int E = in_sizes[1] / 2;    // 3200000
  const int G = out_size / 16;      // 1024
  const int* src = ei;
  const int* dst = ei + E;
  const int nbuckets = (N + ((1 << BSHIFT) - 1)) >> BSHIFT;  // 98

  char* ws = (char*)d_ws;
  size_t off = 0;
  auto alloc = [&](size_t bytes) -> void* {
    void* p = ws + off;
    off += (bytes + 511) & ~(size_t)511;
    return p;
  };
  int*   deg    = (int*)alloc((size_t)N * 4);
  int*   offs   = (int*)alloc(((size_t)N + 1) * 4);
  int*   cursor = (int*)alloc((size_t)N * 4);
  float* dinv   = (float*)alloc((size_t)N * 4);
  int*   bsum   = (int*)alloc(1024);
  int*   gstart = (int*)alloc(((size_t)G + 1) * 4);
  int*   bucket_cnt = (int*)alloc(512);
  int*   csr    = (int*)alloc((size_t)E * 4);
  __half* hbuf  = (__half*)alloc((size_t)N * 64 * 2);   // gemm out (fp16)
  float*  abuf  = (float*)alloc((size_t)N * 64 * 4);    // agg out (fp32)
  float*  pooled = (float*)alloc((size_t)G * 32 * 4);
  // partition scratch (30.6MB) aliases hbuf+abuf (38.4MB): only used before
  // the first GEMM writes hbuf.
  unsigned long long* part = (unsigned long long*)hbuf;
  (void)ws_size; (void)n_in;

  const int nb = (N + 1023) / 1024;  // scan blocks

  // --- CSR build (reused by all 3 layers) ---
  zero_int_kernel<<<(N + 255) / 256, 256, 0, stream>>>(deg, N);
  zero_int_kernel<<<1, 128, 0, stream>>>(bucket_cnt, nbuckets);
  count_deg_kernel<<<(E + 255) / 256, 256, 0, stream>>>(dst, deg, E);
  scan_blocks_kernel<<<nb, 256, 0, stream>>>(deg, offs, bsum, dinv, N);
  scan_bsums_kernel<<<1, 256, 0, stream>>>(bsum, nb);
  scan_finalize_kernel<<<(N + 255) / 256, 256, 0, stream>>>(offs, cursor, bsum, N, E);
  partition_kernel<<<(E + 4095) / 4096, 256, 0, stream>>>(src, dst, bucket_cnt, part,
                                                          E, nbuckets);
  const int pbb = 16;  // blocks per bucket
  fill_bucket_kernel<<<nbuckets * pbb, 256, 0, stream>>>(part, bucket_cnt, cursor,
                                                         csr, pbb);

  // --- layer 1: 128 -> 64 ---
  gemm_kernel<128, 64><<<(N + 31) / 32, 256, 0, stream>>>(x, W1, hbuf, N);
  agg_kernel<64><<<(N + 3) / 4, 256, 0, stream>>>(hbuf, offs, csr, dinv, b1, abuf, N);
  // --- layer 2: 64 -> 64 ---
  gemm_kernel<64, 64><<<(N + 31) / 32, 256, 0, stream>>>(abuf, W2, hbuf, N);
  agg_kernel<64><<<(N + 3) / 4, 256, 0, stream>>>(hbuf, offs, csr, dinv, b2, abuf, N);
  // --- layer 3: 64 -> 32 ---
  gemm_kernel<64, 32><<<(N + 31) / 32, 256, 0, stream>>>(abuf, W3, hbuf, N);
  agg_kernel<32><<<(N + 7) / 8, 256, 0, stream>>>(hbuf, offs, csr, dinv, b3, abuf, N);

  // --- pool + head ---
  graph_ranges_kernel<<<(G + 256) / 256, 256, 0, stream>>>(batch, gstart, N, G);
  pool_kernel<<<(G + 3) / 4, 256, 0, stream>>>(abuf, gstart, pooled, G);
  head_kernel<<<(G + 255) / 256, 256, 0, stream>>>(pooled, Wc1, bc1, Wc2, bc2,
                                                   (float*)d_out, G);
}

// Round 3
// 546.765 us; speedup vs baseline: 1.6500x; 1.3922x over previous
//
#include <hip/hip_runtime.h>
#include <hip/hip_bf16.h>
#include <hip/hip_fp16.h>
#include <math.h>

// ---------------------------------------------------------------------------
// ActivityRecognitionGCN: 3x GCNConv(+ReLU) -> mean pool per graph -> MLP head
// N=100000 nodes, E=3.2M edges, G=1024 graphs, F: 128->64->64->32
// R2 -> R3:
//  * fill: LDS-staged per-bucket csr window (one block per bucket, 256-node
//    buckets). R2's pbb=16 spread windows across XCDs -> 170MB HBM writes;
//    LDS staging + coalesced stream-out writes exactly 12.8MB.
//  * partition: u32 payload ((dst&255)<<17|src), halves scatter bytes.
//  * agg: half4 (8B) per-lane feature loads, F/4 lanes per node -> one wave
//    processes 4 nodes; 4x fewer instructions per edge.
// ---------------------------------------------------------------------------

constexpr int BSHIFT = 8;         // bucket = dst >> 8 (256 nodes per bucket)
constexpr int BMASK  = 255;
constexpr int BCAP   = 10240;     // bucket capacity (mean 8184, +22 sigma)

__global__ void zero_int_kernel(int* __restrict__ p, int n) {
  int i = blockIdx.x * blockDim.x + threadIdx.x;
  if (i < n) p[i] = 0;
}

__global__ void count_deg_kernel(const int* __restrict__ dst, int* __restrict__ deg, int E) {
  int i = blockIdx.x * blockDim.x + threadIdx.x;
  if (i < E) atomicAdd(&deg[dst[i]], 1);
}

// Block scans 1024 elements (4/thread). Writes within-block exclusive scan,
// block totals, and dinv = (deg+1)^-0.5.
__global__ __launch_bounds__(256) void scan_blocks_kernel(const int* __restrict__ deg,
    int* __restrict__ offs, int* __restrict__ bsum, float* __restrict__ dinv, int n) {
  __shared__ int sh[256];
  const int tid = threadIdx.x;
  const int base = blockIdx.x * 1024 + tid * 4;
  int v[4];
#pragma unroll
  for (int j = 0; j < 4; ++j) v[j] = (base + j < n) ? deg[base + j] : 0;
#pragma unroll
  for (int j = 0; j < 4; ++j)
    if (base + j < n) dinv[base + j] = 1.0f / sqrtf((float)(v[j] + 1));
  int s = v[0] + v[1] + v[2] + v[3];
  sh[tid] = s;
  __syncthreads();
  for (int d = 1; d < 256; d <<= 1) {
    int t = 0;
    if (tid >= d) t = sh[tid - d];
    __syncthreads();
    if (tid >= d) sh[tid] += t;
    __syncthreads();
  }
  int excl = sh[tid] - s;
  if (tid == 255) bsum[blockIdx.x] = sh[tid];
  int run = excl;
#pragma unroll
  for (int j = 0; j < 4; ++j) {
    if (base + j < n) offs[base + j] = run;
    run += v[j];
  }
}

__global__ __launch_bounds__(256) void scan_bsums_kernel(int* __restrict__ bsum, int nb) {
  __shared__ int sh[256];
  const int tid = threadIdx.x;
  int s = (tid < nb) ? bsum[tid] : 0;
  sh[tid] = s;
  __syncthreads();
  for (int d = 1; d < 256; d <<= 1) {
    int t = 0;
    if (tid >= d) t = sh[tid - d];
    __syncthreads();
    if (tid >= d) sh[tid] += t;
    __syncthreads();
  }
  if (tid < nb) bsum[tid] = sh[tid] - s;  // exclusive
}

__global__ void scan_finalize_kernel(int* __restrict__ offs, const int* __restrict__ bsum,
                                     int n, int total) {
  int i = blockIdx.x * blockDim.x + threadIdx.x;
  if (i < n) offs[i] = offs[i] + bsum[i >> 10];
  if (i == 0) offs[n] = total;
}

// Partition edges into 256-node buckets. Two passes over the block's 8192
// edges (second read is L2-hot): count per-bucket in LDS, reserve global
// spans, then scatter u32 payload (dst_low<<17 | src).
__global__ __launch_bounds__(256) void partition_kernel(const int* __restrict__ src,
    const int* __restrict__ dst, int* __restrict__ bucket_cnt,
    unsigned* __restrict__ part, int E, int nbuckets) {
  __shared__ int lcnt[512];
  __shared__ int lbase[512];
  const int tid = threadIdx.x;
  const int base = blockIdx.x * 8192;
  const int lim = min(8192, E - base);
  for (int b = tid; b < nbuckets; b += 256) lcnt[b] = 0;
  __syncthreads();
  for (int j = tid; j < lim; j += 256)
    atomicAdd(&lcnt[dst[base + j] >> BSHIFT], 1);
  __syncthreads();
  for (int b = tid; b < nbuckets; b += 256) {
    lbase[b] = atomicAdd(&bucket_cnt[b], lcnt[b]);
    lcnt[b] = 0;
  }
  __syncthreads();
  for (int j = tid; j < lim; j += 256) {
    int d = dst[base + j], s = src[base + j];
    int b = d >> BSHIFT;
    int pos = lbase[b] + atomicAdd(&lcnt[b], 1);
    if (pos < BCAP)
      part[(size_t)b * BCAP + pos] = ((unsigned)(d & BMASK) << 17) | (unsigned)s;
  }
}

// One block per bucket: build the bucket's csr window in LDS (local cursors,
// LDS atomics), then stream it out coalesced. All HBM writes are full lines
// from a single block -> WRITE_SIZE == csr bytes.
__global__ __launch_bounds__(256) void fill_bucket_kernel(
    const unsigned* __restrict__ part, const int* __restrict__ bucket_cnt,
    const int* __restrict__ offs, int* __restrict__ csr, int N) {
  __shared__ int lwin[BCAP];
  __shared__ int lcur[256];
  __shared__ int loff[257];
  const int b = blockIdx.x;
  const int nb0 = b << BSHIFT;
  const int nn = min(1 << BSHIFT, N - nb0);
  for (int i = threadIdx.x; i <= nn; i += 256) loff[i] = offs[nb0 + i];
  __syncthreads();
  const int base = loff[0];
  const int wl = loff[nn] - base;
  if (threadIdx.x < nn) lcur[threadIdx.x] = loff[threadIdx.x] - base;
  __syncthreads();
  const int cnt = min(bucket_cnt[b], BCAP);
  for (int i = threadIdx.x; i < cnt; i += 256) {
    unsigned v = part[(size_t)b * BCAP + i];
    int dl = (int)(v >> 17);
    int s = (int)(v & 0x1FFFF);
    int pos = atomicAdd(&lcur[dl], 1);
    if (pos < BCAP) lwin[pos] = s;
    else csr[base + pos] = s;  // statistically unreachable fallback
  }
  __syncthreads();
  const int m = min(wl, BCAP);
  for (int i = threadIdx.x; i < m; i += 256) csr[base + i] = lwin[i];
}

// ---------------------------------------------------------------------------
// Dense GEMM: Y[N,M](fp16) = X[N,K](fp32) @ W[K,M].  W staged in LDS.
// ---------------------------------------------------------------------------
template <int K, int M>
__global__ __launch_bounds__(256) void gemm_kernel(const float* __restrict__ X,
    const float* __restrict__ W, __half* __restrict__ Y, int n) {
  constexpr int RPB = 32;
  constexpr int XST = K + 4;
  constexpr int MC = M / 16;
  __shared__ __align__(16) float Ws[K * M];
  __shared__ __align__(16) float Xs[RPB * XST];
  const int tid = threadIdx.x;
  const int row0 = blockIdx.x * RPB;
  for (int i = tid * 4; i < K * M; i += 1024)
    *reinterpret_cast<float4*>(&Ws[i]) = *reinterpret_cast<const float4*>(&W[i]);
  for (int i = tid * 4; i < RPB * K; i += 1024) {
    int r = i / K, k = i - r * K;
    int gr = row0 + r;
    float4 v = make_float4(0.f, 0.f, 0.f, 0.f);
    if (gr < n) v = *reinterpret_cast<const float4*>(&X[(size_t)gr * K + k]);
    *reinterpret_cast<float4*>(&Xs[r * XST + k]) = v;
  }
  __syncthreads();
  const int rt = tid & 15;
  const int c = tid >> 4;
  float acc[2][MC];
#pragma unroll
  for (int rr = 0; rr < 2; ++rr)
#pragma unroll
    for (int j = 0; j < MC; ++j) acc[rr][j] = 0.f;
  for (int k4 = 0; k4 < K; k4 += 4) {
    float4 xv[2];
#pragma unroll
    for (int rr = 0; rr < 2; ++rr)
      xv[rr] = *reinterpret_cast<const float4*>(&Xs[(rt + 16 * rr) * XST + k4]);
    const float* xf0 = reinterpret_cast<const float*>(&xv[0]);
    const float* xf1 = reinterpret_cast<const float*>(&xv[1]);
#pragma unroll
    for (int kk = 0; kk < 4; ++kk) {
      float w[MC];
#pragma unroll
      for (int j = 0; j < MC; ++j) w[j] = Ws[(k4 + kk) * M + c * MC + j];
      float x0 = xf0[kk], x1 = xf1[kk];
#pragma unroll
      for (int j = 0; j < MC; ++j) {
        acc[0][j] += x0 * w[j];
        acc[1][j] += x1 * w[j];
      }
    }
  }
#pragma unroll
  for (int rr = 0; rr < 2; ++rr) {
    int gr = row0 + rt + 16 * rr;
    if (gr < n) {
#pragma unroll
      for (int j = 0; j < MC; ++j)
        Y[(size_t)gr * M + c * MC + j] = __float2half(acc[rr][j]);
    }
  }
}

// ---------------------------------------------------------------------------
// Gather-aggregate, vectorized: F/4 lanes per node, each lane owns 4 features
// (one 8B half4 load per edge). One wave serves 4 nodes (F=64) / 8 (F=32).
// ---------------------------------------------------------------------------
__device__ inline float4 h4_to_f4(float2 r) {
  __half2 lo = *reinterpret_cast<__half2*>(&r.x);
  __half2 hi = *reinterpret_cast<__half2*>(&r.y);
  float2 a = __half22float2(lo), b = __half22float2(hi);
  return make_float4(a.x, a.y, b.x, b.y);
}

template <int F>
__global__ __launch_bounds__(256) void agg_kernel(const __half* __restrict__ h,
    const int* __restrict__ offs, const int* __restrict__ csr,
    const float* __restrict__ dinv, const float* __restrict__ bias,
    float* __restrict__ out, int n) {
  constexpr int GPN = F / 4;        // lanes per node
  constexpr int NPB = 256 / GPN;    // nodes per block
  const int node = blockIdx.x * NPB + threadIdx.x / GPN;
  const int fl = (threadIdx.x % GPN) * 4;
  if (node >= n) return;
  const int e0 = offs[node], e1 = offs[node + 1];
  const float di = dinv[node];
  float4 acc;
  {
    float2 r = *reinterpret_cast<const float2*>(h + (size_t)node * F + fl);
    float4 v = h4_to_f4(r);
    float w = di * di;
    acc = make_float4(w * v.x, w * v.y, w * v.z, w * v.w);
  }
  int e = e0;
  for (; e + 4 <= e1; e += 4) {
    int s0 = csr[e], s1 = csr[e + 1], s2 = csr[e + 2], s3 = csr[e + 3];
    float w0 = di * dinv[s0], w1 = di * dinv[s1];
    float w2 = di * dinv[s2], w3 = di * dinv[s3];
    float2 r0 = *reinterpret_cast<const float2*>(h + (size_t)s0 * F + fl);
    float2 r1 = *reinterpret_cast<const float2*>(h + (size_t)s1 * F + fl);
    float2 r2 = *reinterpret_cast<const float2*>(h + (size_t)s2 * F + fl);
    float2 r3 = *reinterpret_cast<const float2*>(h + (size_t)s3 * F + fl);
    float4 v0 = h4_to_f4(r0), v1 = h4_to_f4(r1);
    float4 v2 = h4_to_f4(r2), v3 = h4_to_f4(r3);
    acc.x += w0 * v0.x + w1 * v1.x + w2 * v2.x + w3 * v3.x;
    acc.y += w0 * v0.y + w1 * v1.y + w2 * v2.y + w3 * v3.y;
    acc.z += w0 * v0.z + w1 * v1.z + w2 * v2.z + w3 * v3.z;
    acc.w += w0 * v0.w + w1 * v1.w + w2 * v2.w + w3 * v3.w;
  }
  for (; e < e1; ++e) {
    int s = csr[e];
    float w = di * dinv[s];
    float2 r = *reinterpret_cast<const float2*>(h + (size_t)s * F + fl);
    float4 v = h4_to_f4(r);
    acc.x += w * v.x; acc.y += w * v.y; acc.z += w * v.z; acc.w += w * v.w;
  }
  const float4 b4 = *reinterpret_cast<const float4*>(&bias[fl]);
  float4 res = make_float4(fmaxf(acc.x + b4.x, 0.f), fmaxf(acc.y + b4.y, 0.f),
                           fmaxf(acc.z + b4.z, 0.f), fmaxf(acc.w + b4.w, 0.f));
  *reinterpret_cast<float4*>(&out[(size_t)node * F + fl]) = res;
}

// batch is sorted: per-graph node range via binary search.
__global__ void graph_ranges_kernel(const int* __restrict__ batch, int* __restrict__ gstart,
                                    int n, int G) {
  int g = blockIdx.x * blockDim.x + threadIdx.x;
  if (g > G) return;
  int lo = 0, hi = n;
  while (lo < hi) {
    int mid = (lo + hi) >> 1;
    if (batch[mid] < g) lo = mid + 1; else hi = mid;
  }
  gstart[g] = lo;
}

// One wave per graph: lane = (feature, node parity). Mean over the range.
__global__ __launch_bounds__(256) void pool_kernel(const float* __restrict__ h,
    const int* __restrict__ gstart, float* __restrict__ pooled, int G) {
  int g = blockIdx.x * 4 + (threadIdx.x >> 6);
  if (g >= G) return;
  int lane = threadIdx.x & 63;
  int f = lane & 31, sub = lane >> 5;
  int s = gstart[g], e = gstart[g + 1];
  float acc = 0.f;
  for (int i = s + sub; i < e; i += 2) acc += h[(size_t)i * 32 + f];
  acc += __shfl_xor(acc, 32);
  float mean = acc / fmaxf((float)(e - s), 1.0f);
  if (sub == 0) pooled[g * 32 + f] = mean;
}

// One thread per graph: z = relu(p@Wc1+bc1); logits = z@Wc2+bc2; log_softmax.
__global__ __launch_bounds__(256) void head_kernel(const float* __restrict__ pooled,
    const float* __restrict__ Wc1, const float* __restrict__ bc1,
    const float* __restrict__ Wc2, const float* __restrict__ bc2,
    float* __restrict__ out, int G) {
  int g = blockIdx.x * blockDim.x + threadIdx.x;
  if (g >= G) return;
  float p[32];
#pragma unroll
  for (int k = 0; k < 32; ++k) p[k] = pooled[g * 32 + k];
  float z[16];
#pragma unroll
  for (int j = 0; j < 16; ++j) {
    float a = bc1[j];
#pragma unroll
    for (int k = 0; k < 32; ++k) a += p[k] * Wc1[k * 16 + j];
    z[j] = fmaxf(a, 0.f);
  }
  float lg[16];
  float m = -1e30f;
#pragma unroll
  for (int j = 0; j < 16; ++j) {
    float a = bc2[j];
#pragma unroll
    for (int k = 0; k < 16; ++k) a += z[k] * Wc2[k * 16 + j];
    lg[j] = a;
    m = fmaxf(m, a);
  }
  float ssum = 0.f;
#pragma unroll
  for (int j = 0; j < 16; ++j) ssum += expf(lg[j] - m);
  float lse = logf(ssum);
#pragma unroll
  for (int j = 0; j < 16; ++j) out[g * 16 + j] = lg[j] - m - lse;
}

extern "C" void kernel_launch(void* const* d_in, const int* in_sizes, int n_in,
                              void* d_out, int out_size, void* d_ws, size_t ws_size,
                              hipStream_t stream) {
  const float* x   = (const float*)d_in[0];
  const int*   ei  = (const int*)d_in[1];
  const int*   batch = (const int*)d_in[2];
  const float* W1 = (const float*)d_in[3];
  const float* b1 = (const float*)d_in[4];
  const float* W2 = (const float*)d_in[5];
  const float* b2 = (const float*)d_in[6];
  const float* W3 = (const float*)d_in[7];
  const float* b3 = (const float*)d_in[8];
  const float* Wc1 = (const float*)d_in[9];
  const float* bc1 = (const float*)d_in[10];
  const float* Wc2 = (const float*)d_in[11];
  const float* bc2 = (const float*)d_in[12];

  const int N = in_sizes[2];        // 100000
  const int E = in_sizes[1] / 2;    // 3200000
  const int G = out_size / 16;      // 1024
  const int* src = ei;
  const int* dst = ei + E;
  const int nbuckets = (N + ((1 << BSHIFT) - 1)) >> BSHIFT;  // 391

  char* ws = (char*)d_ws;
  size_t off = 0;
  auto alloc = [&](size_t bytes) -> void* {
    void* p = ws + off;
    off += (bytes + 511) & ~(size_t)511;
    return p;
  };
  int*   deg    = (int*)alloc((size_t)N * 4);
  int*   offs   = (int*)alloc(((size_t)N + 1) * 4);
  float* dinv   = (float*)alloc((size_t)N * 4);
  int*   bsum   = (int*)alloc(1024);
  int*   gstart = (int*)alloc(((size_t)G + 1) * 4);
  int*   bucket_cnt = (int*)alloc((size_t)nbuckets * 4);
  int*   csr    = (int*)alloc((size_t)E * 4);
  __half* hbuf  = (__half*)alloc((size_t)N * 64 * 2);   // gemm out (fp16)
  float*  abuf  = (float*)alloc((size_t)N * 64 * 4);    // agg out (fp32)
  float*  pooled = (float*)alloc((size_t)G * 32 * 4);
  // partition scratch (391*10240*4 = 16MB) aliases hbuf(12.8MB)+abuf head:
  // only used before the first GEMM writes hbuf / agg1 writes abuf.
  unsigned* part = (unsigned*)hbuf;
  (void)ws_size; (void)n_in;

  const int nb = (N + 1023) / 1024;  // scan blocks

  // --- CSR build (reused by all 3 layers) ---
  zero_int_kernel<<<(N + 255) / 256, 256, 0, stream>>>(deg, N);
  zero_int_kernel<<<(nbuckets + 255) / 256, 256, 0, stream>>>(bucket_cnt, nbuckets);
  count_deg_kernel<<<(E + 255) / 256, 256, 0, stream>>>(dst, deg, E);
  scan_blocks_kernel<<<nb, 256, 0, stream>>>(deg, offs, bsum, dinv, N);
  scan_bsums_kernel<<<1, 256, 0, stream>>>(bsum, nb);
  scan_finalize_kernel<<<(N + 255) / 256, 256, 0, stream>>>(offs, bsum, N, E);
  partition_kernel<<<(E + 8191) / 8192, 256, 0, stream>>>(src, dst, bucket_cnt, part,
                                                          E, nbuckets);
  fill_bucket_kernel<<<nbuckets, 256, 0, stream>>>(part, bucket_cnt, offs, csr, N);

  // --- layer 1: 128 -> 64 ---
  gemm_kernel<128, 64><<<(N + 31) / 32, 256, 0, stream>>>(x, W1, hbuf, N);
  agg_kernel<64><<<(N + 15) / 16, 256, 0, stream>>>(hbuf, offs, csr, dinv, b1, abuf, N);
  // --- layer 2: 64 -> 64 ---
  gemm_kernel<64, 64><<<(N + 31) / 32, 256, 0, stream>>>(abuf, W2, hbuf, N);
  agg_kernel<64><<<(N + 15) / 16, 256, 0, stream>>>(hbuf, offs, csr, dinv, b2, abuf, N);
  // --- layer 3: 64 -> 32 ---
  gemm_kernel<64, 32><<<(N + 31) / 32, 256, 0, stream>>>(abuf, W3, hbuf, N);
  agg_kernel<32><<<(N + 31) / 32, 256, 0, stream>>>(hbuf, offs, csr, dinv, b3, abuf, N);

  // --- pool + head ---
  graph_ranges_kernel<<<(G + 256) / 256, 256, 0, stream>>>(batch, gstart, N, G);
  pool_kernel<<<(G + 3) / 4, 256, 0, stream>>>(abuf, gstart, pooled, G);
  head_kernel<<<(G + 255) / 256, 256, 0, stream>>>(pooled, Wc1, bc1, Wc2, bc2,
                                                   (float*)d_out, G);
}

// Round 4
// 414.888 us; speedup vs baseline: 2.1744x; 1.3179x over previous
//
#include <hip/hip_runtime.h>
#include <hip/hip_bf16.h>
#include <hip/hip_fp16.h>
#include <math.h>

// ---------------------------------------------------------------------------
// ActivityRecognitionGCN: 3x GCNConv(+ReLU) -> mean pool per graph -> MLP head
// N=100000 nodes, E=3.2M edges, G=1024 graphs, F: 128->64->64->32
// R3 -> R4:
//  * Killed count_deg_kernel (128us; 3.2M scattered global atomics -> 100MB
//    write-allocate traffic). Degrees are now counted with LDS atomics inside
//    fill_bucket (bucket = 256 nodes); offs = bucket_base (391-wide scan of
//    bucket_cnt) + in-LDS 256-wide exclusive scan. dinv computed there too.
//    Deletes 5 kernels; CSR build = zero + partition + tiny scan + fill.
// ---------------------------------------------------------------------------

constexpr int BSHIFT = 8;         // bucket = dst >> 8 (256 nodes per bucket)
constexpr int BMASK  = 255;
constexpr int BCAP   = 10240;     // bucket capacity (mean 8192, +22 sigma)

__global__ void zero_int_kernel(int* __restrict__ p, int n) {
  int i = blockIdx.x * blockDim.x + threadIdx.x;
  if (i < n) p[i] = 0;
}

// Partition edges into 256-node buckets. Two passes over the block's 8192
// edges (second read is L2-hot): count per-bucket in LDS, reserve global
// spans, then scatter u32 payload (dst_low<<17 | src).
__global__ __launch_bounds__(256) void partition_kernel(const int* __restrict__ src,
    const int* __restrict__ dst, int* __restrict__ bucket_cnt,
    unsigned* __restrict__ part, int E, int nbuckets) {
  __shared__ int lcnt[512];
  __shared__ int lbase[512];
  const int tid = threadIdx.x;
  const int base = blockIdx.x * 8192;
  const int lim = min(8192, E - base);
  for (int b = tid; b < nbuckets; b += 256) lcnt[b] = 0;
  __syncthreads();
  for (int j = tid; j < lim; j += 256)
    atomicAdd(&lcnt[dst[base + j] >> BSHIFT], 1);
  __syncthreads();
  for (int b = tid; b < nbuckets; b += 256) {
    lbase[b] = atomicAdd(&bucket_cnt[b], lcnt[b]);
    lcnt[b] = 0;
  }
  __syncthreads();
  for (int j = tid; j < lim; j += 256) {
    int d = dst[base + j], s = src[base + j];
    int b = d >> BSHIFT;
    int pos = lbase[b] + atomicAdd(&lcnt[b], 1);
    if (pos < BCAP)
      part[(size_t)b * BCAP + pos] = ((unsigned)(d & BMASK) << 17) | (unsigned)s;
  }
}

// Exclusive scan of bucket_cnt (nb <= 512) in a single block.
__global__ __launch_bounds__(256) void scan_buckets_kernel(const int* __restrict__ cnt,
    int* __restrict__ base, int nb) {
  __shared__ int sh[512];
  const int t = threadIdx.x;
  sh[t] = (t < nb) ? cnt[t] : 0;
  sh[t + 256] = (t + 256 < nb) ? cnt[t + 256] : 0;
  __syncthreads();
  for (int d = 1; d < 512; d <<= 1) {
    int v0 = 0, v1 = 0;
    if (t >= d) v0 = sh[t - d];
    if (t + 256 >= d) v1 = sh[t + 256 - d];
    __syncthreads();
    if (t >= d) sh[t] += v0;
    if (t + 256 >= d) sh[t + 256] += v1;
    __syncthreads();
  }
  if (t < nb) base[t] = (t == 0) ? 0 : sh[t - 1];
  if (t + 256 < nb) base[t + 256] = sh[t + 255];
}

// One block per bucket: LDS histogram of per-node degree -> offs/dinv
// (coalesced writes), then place edges into the LDS csr window via local
// cursors, then stream out coalesced. WRITE_SIZE == csr bytes.
__global__ __launch_bounds__(256) void fill_bucket_kernel(
    const unsigned* __restrict__ part, const int* __restrict__ bucket_cnt,
    const int* __restrict__ bucket_base, int* __restrict__ offs,
    float* __restrict__ dinv, int* __restrict__ csr, int N, int E) {
  __shared__ int lwin[BCAP];
  __shared__ int ldeg[256];
  __shared__ int lscan[256];
  const int b = blockIdx.x;
  const int t = threadIdx.x;
  const int nb0 = b << BSHIFT;
  const int nn = min(1 << BSHIFT, N - nb0);
  const int cnt = min(bucket_cnt[b], BCAP);
  const int wbase = bucket_base[b];
  ldeg[t] = 0;
  __syncthreads();
  // pass 1: per-node degree histogram
  for (int i = t; i < cnt; i += 256)
    atomicAdd(&ldeg[part[(size_t)b * BCAP + i] >> 17], 1);
  __syncthreads();
  // exclusive scan over 256 node-degrees (Hillis-Steele)
  const int myv = ldeg[t];
  lscan[t] = myv;
  __syncthreads();
  for (int d = 1; d < 256; d <<= 1) {
    int v = 0;
    if (t >= d) v = lscan[t - d];
    __syncthreads();
    if (t >= d) lscan[t] += v;
    __syncthreads();
  }
  const int excl = lscan[t] - myv;
  if (t < nn) {
    offs[nb0 + t] = wbase + excl;
    dinv[nb0 + t] = 1.0f / sqrtf((float)(myv + 1));
  }
  if (t == 0 && nb0 + nn == N) offs[N] = E;
  ldeg[t] = excl;  // becomes local cursor
  __syncthreads();
  // pass 2: place (part segment is L2-hot from pass 1)
  for (int i = t; i < cnt; i += 256) {
    unsigned v = part[(size_t)b * BCAP + i];
    int pos = atomicAdd(&ldeg[v >> 17], 1);
    lwin[pos] = (int)(v & 0x1FFFF);
  }
  __syncthreads();
  // stream out coalesced
  for (int i = t; i < cnt; i += 256) csr[wbase + i] = lwin[i];
}

// ---------------------------------------------------------------------------
// Dense GEMM: Y[N,M](fp16) = X[N,K](fp32) @ W[K,M].  W staged in LDS.
// ---------------------------------------------------------------------------
template <int K, int M>
__global__ __launch_bounds__(256) void gemm_kernel(const float* __restrict__ X,
    const float* __restrict__ W, __half* __restrict__ Y, int n) {
  constexpr int RPB = 32;
  constexpr int XST = K + 4;
  constexpr int MC = M / 16;
  __shared__ __align__(16) float Ws[K * M];
  __shared__ __align__(16) float Xs[RPB * XST];
  const int tid = threadIdx.x;
  const int row0 = blockIdx.x * RPB;
  for (int i = tid * 4; i < K * M; i += 1024)
    *reinterpret_cast<float4*>(&Ws[i]) = *reinterpret_cast<const float4*>(&W[i]);
  for (int i = tid * 4; i < RPB * K; i += 1024) {
    int r = i / K, k = i - r * K;
    int gr = row0 + r;
    float4 v = make_float4(0.f, 0.f, 0.f, 0.f);
    if (gr < n) v = *reinterpret_cast<const float4*>(&X[(size_t)gr * K + k]);
    *reinterpret_cast<float4*>(&Xs[r * XST + k]) = v;
  }
  __syncthreads();
  const int rt = tid & 15;
  const int c = tid >> 4;
  float acc[2][MC];
#pragma unroll
  for (int rr = 0; rr < 2; ++rr)
#pragma unroll
    for (int j = 0; j < MC; ++j) acc[rr][j] = 0.f;
  for (int k4 = 0; k4 < K; k4 += 4) {
    float4 xv[2];
#pragma unroll
    for (int rr = 0; rr < 2; ++rr)
      xv[rr] = *reinterpret_cast<const float4*>(&Xs[(rt + 16 * rr) * XST + k4]);
    const float* xf0 = reinterpret_cast<const float*>(&xv[0]);
    const float* xf1 = reinterpret_cast<const float*>(&xv[1]);
#pragma unroll
    for (int kk = 0; kk < 4; ++kk) {
      float w[MC];
#pragma unroll
      for (int j = 0; j < MC; ++j) w[j] = Ws[(k4 + kk) * M + c * MC + j];
      float x0 = xf0[kk], x1 = xf1[kk];
#pragma unroll
      for (int j = 0; j < MC; ++j) {
        acc[0][j] += x0 * w[j];
        acc[1][j] += x1 * w[j];
      }
    }
  }
#pragma unroll
  for (int rr = 0; rr < 2; ++rr) {
    int gr = row0 + rt + 16 * rr;
    if (gr < n) {
#pragma unroll
      for (int j = 0; j < MC; ++j)
        Y[(size_t)gr * M + c * MC + j] = __float2half(acc[rr][j]);
    }
  }
}

// ---------------------------------------------------------------------------
// Gather-aggregate, vectorized: F/4 lanes per node, each lane owns 4 features
// (one 8B half4 load per edge). One wave serves 4 nodes (F=64) / 8 (F=32).
// ---------------------------------------------------------------------------
__device__ inline float4 h4_to_f4(float2 r) {
  __half2 lo = *reinterpret_cast<__half2*>(&r.x);
  __half2 hi = *reinterpret_cast<__half2*>(&r.y);
  float2 a = __half22float2(lo), b = __half22float2(hi);
  return make_float4(a.x, a.y, b.x, b.y);
}

template <int F>
__global__ __launch_bounds__(256) void agg_kernel(const __half* __restrict__ h,
    const int* __restrict__ offs, const int* __restrict__ csr,
    const float* __restrict__ dinv, const float* __restrict__ bias,
    float* __restrict__ out, int n) {
  constexpr int GPN = F / 4;        // lanes per node
  constexpr int NPB = 256 / GPN;    // nodes per block
  const int node = blockIdx.x * NPB + threadIdx.x / GPN;
  const int fl = (threadIdx.x % GPN) * 4;
  if (node >= n) return;
  const int e0 = offs[node], e1 = offs[node + 1];
  const float di = dinv[node];
  float4 acc;
  {
    float2 r = *reinterpret_cast<const float2*>(h + (size_t)node * F + fl);
    float4 v = h4_to_f4(r);
    float w = di * di;
    acc = make_float4(w * v.x, w * v.y, w * v.z, w * v.w);
  }
  int e = e0;
  for (; e + 4 <= e1; e += 4) {
    int s0 = csr[e], s1 = csr[e + 1], s2 = csr[e + 2], s3 = csr[e + 3];
    float w0 = di * dinv[s0], w1 = di * dinv[s1];
    float w2 = di * dinv[s2], w3 = di * dinv[s3];
    float2 r0 = *reinterpret_cast<const float2*>(h + (size_t)s0 * F + fl);
    float2 r1 = *reinterpret_cast<const float2*>(h + (size_t)s1 * F + fl);
    float2 r2 = *reinterpret_cast<const float2*>(h + (size_t)s2 * F + fl);
    float2 r3 = *reinterpret_cast<const float2*>(h + (size_t)s3 * F + fl);
    float4 v0 = h4_to_f4(r0), v1 = h4_to_f4(r1);
    float4 v2 = h4_to_f4(r2), v3 = h4_to_f4(r3);
    acc.x += w0 * v0.x + w1 * v1.x + w2 * v2.x + w3 * v3.x;
    acc.y += w0 * v0.y + w1 * v1.y + w2 * v2.y + w3 * v3.y;
    acc.z += w0 * v0.z + w1 * v1.z + w2 * v2.z + w3 * v3.z;
    acc.w += w0 * v0.w + w1 * v1.w + w2 * v2.w + w3 * v3.w;
  }
  for (; e < e1; ++e) {
    int s = csr[e];
    float w = di * dinv[s];
    float2 r = *reinterpret_cast<const float2*>(h + (size_t)s * F + fl);
    float4 v = h4_to_f4(r);
    acc.x += w * v.x; acc.y += w * v.y; acc.z += w * v.z; acc.w += w * v.w;
  }
  const float4 b4 = *reinterpret_cast<const float4*>(&bias[fl]);
  float4 res = make_float4(fmaxf(acc.x + b4.x, 0.f), fmaxf(acc.y + b4.y, 0.f),
                           fmaxf(acc.z + b4.z, 0.f), fmaxf(acc.w + b4.w, 0.f));
  *reinterpret_cast<float4*>(&out[(size_t)node * F + fl]) = res;
}

// batch is sorted: per-graph node range via binary search.
__global__ void graph_ranges_kernel(const int* __restrict__ batch, int* __restrict__ gstart,
                                    int n, int G) {
  int g = blockIdx.x * blockDim.x + threadIdx.x;
  if (g > G) return;
  int lo = 0, hi = n;
  while (lo < hi) {
    int mid = (lo + hi) >> 1;
    if (batch[mid] < g) lo = mid + 1; else hi = mid;
  }
  gstart[g] = lo;
}

// One wave per graph: lane = (feature, node parity). Mean over the range.
__global__ __launch_bounds__(256) void pool_kernel(const float* __restrict__ h,
    const int* __restrict__ gstart, float* __restrict__ pooled, int G) {
  int g = blockIdx.x * 4 + (threadIdx.x >> 6);
  if (g >= G) return;
  int lane = threadIdx.x & 63;
  int f = lane & 31, sub = lane >> 5;
  int s = gstart[g], e = gstart[g + 1];
  float acc = 0.f;
  for (int i = s + sub; i < e; i += 2) acc += h[(size_t)i * 32 + f];
  acc += __shfl_xor(acc, 32);
  float mean = acc / fmaxf((float)(e - s), 1.0f);
  if (sub == 0) pooled[g * 32 + f] = mean;
}

// One thread per graph: z = relu(p@Wc1+bc1); logits = z@Wc2+bc2; log_softmax.
__global__ __launch_bounds__(256) void head_kernel(const float* __restrict__ pooled,
    const float* __restrict__ Wc1, const float* __restrict__ bc1,
    const float* __restrict__ Wc2, const float* __restrict__ bc2,
    float* __restrict__ out, int G) {
  int g = blockIdx.x * blockDim.x + threadIdx.x;
  if (g >= G) return;
  float p[32];
#pragma unroll
  for (int k = 0; k < 32; ++k) p[k] = pooled[g * 32 + k];
  float z[16];
#pragma unroll
  for (int j = 0; j < 16; ++j) {
    float a = bc1[j];
#pragma unroll
    for (int k = 0; k < 32; ++k) a += p[k] * Wc1[k * 16 + j];
    z[j] = fmaxf(a, 0.f);
  }
  float lg[16];
  float m = -1e30f;
#pragma unroll
  for (int j = 0; j < 16; ++j) {
    float a = bc2[j];
#pragma unroll
    for (int k = 0; k < 16; ++k) a += z[k] * Wc2[k * 16 + j];
    lg[j] = a;
    m = fmaxf(m, a);
  }
  float ssum = 0.f;
#pragma unroll
  for (int j = 0; j < 16; ++j) ssum += expf(lg[j] - m);
  float lse = logf(ssum);
#pragma unroll
  for (int j = 0; j < 16; ++j) out[g * 16 + j] = lg[j] - m - lse;
}

extern "C" void kernel_launch(void* const* d_in, const int* in_sizes, int n_in,
                              void* d_out, int out_size, void* d_ws, size_t ws_size,
                              hipStream_t stream) {
  const float* x   = (const float*)d_in[0];
  const int*   ei  = (const int*)d_in[1];
  const int*   batch = (const int*)d_in[2];
  const float* W1 = (const float*)d_in[3];
  const float* b1 = (const float*)d_in[4];
  const float* W2 = (const float*)d_in[5];
  const float* b2 = (const float*)d_in[6];
  const float* W3 = (const float*)d_in[7];
  const float* b3 = (const float*)d_in[8];
  const float* Wc1 = (const float*)d_in[9];
  const float* bc1 = (const float*)d_in[10];
  const float* Wc2 = (const float*)d_in[11];
  const float* bc2 = (const float*)d_in[12];

  const int N = in_sizes[2];        // 100000
  const int E = in_sizes[1] / 2;    // 3200000
  const int G = out_size / 16;      // 1024
  const int* src = ei;
  const int* dst = ei + E;
  const int nbuckets = (N + ((1 << BSHIFT) - 1)) >> BSHIFT;  // 391

  char* ws = (char*)d_ws;
  size_t off = 0;
  auto alloc = [&](size_t bytes) -> void* {
    void* p = ws + off;
    off += (bytes + 511) & ~(size_t)511;
    return p;
  };
  int*   offs   = (int*)alloc(((size_t)N + 1) * 4);
  float* dinv   = (float*)alloc((size_t)N * 4);
  int*   gstart = (int*)alloc(((size_t)G + 1) * 4);
  int*   bucket_cnt  = (int*)alloc(2048);
  int*   bucket_base = (int*)alloc(2048);
  int*   csr    = (int*)alloc((size_t)E * 4);
  __half* hbuf  = (__half*)alloc((size_t)N * 64 * 2);   // gemm out (fp16)
  float*  abuf  = (float*)alloc((size_t)N * 64 * 4);    // agg out (fp32)
  float*  pooled = (float*)alloc((size_t)G * 32 * 4);
  // partition scratch (391*10240*4 = 16MB) aliases hbuf(12.8MB)+abuf head:
  // consumed by fill_bucket before gemm1/agg1 overwrite them.
  unsigned* part = (unsigned*)hbuf;
  (void)ws_size; (void)n_in;

  // --- CSR build (reused by all 3 layers) ---
  zero_int_kernel<<<(nbuckets + 255) / 256, 256, 0, stream>>>(bucket_cnt, nbuckets);
  partition_kernel<<<(E + 8191) / 8192, 256, 0, stream>>>(src, dst, bucket_cnt, part,
                                                          E, nbuckets);
  scan_buckets_kernel<<<1, 256, 0, stream>>>(bucket_cnt, bucket_base, nbuckets);
  fill_bucket_kernel<<<nbuckets, 256, 0, stream>>>(part, bucket_cnt, bucket_base,
                                                   offs, dinv, csr, N, E);

  // --- layer 1: 128 -> 64 ---
  gemm_kernel<128, 64><<<(N + 31) / 32, 256, 0, stream>>>(x, W1, hbuf, N);
  agg_kernel<64><<<(N + 15) / 16, 256, 0, stream>>>(hbuf, offs, csr, dinv, b1, abuf, N);
  // --- layer 2: 64 -> 64 ---
  gemm_kernel<64, 64><<<(N + 31) / 32, 256, 0, stream>>>(abuf, W2, hbuf, N);
  agg_kernel<64><<<(N + 15) / 16, 256, 0, stream>>>(hbuf, offs, csr, dinv, b2, abuf, N);
  // --- layer 3: 64 -> 32 ---
  gemm_kernel<64, 32><<<(N + 31) / 32, 256, 0, stream>>>(abuf, W3, hbuf, N);
  agg_kernel<32><<<(N + 31) / 32, 256, 0, stream>>>(hbuf, offs, csr, dinv, b3, abuf, N);

  // --- pool + head ---
  graph_ranges_kernel<<<(G + 256) / 256, 256, 0, stream>>>(batch, gstart, N, G);
  pool_kernel<<<(G + 3) / 4, 256, 0, stream>>>(abuf, gstart, pooled, G);
  head_kernel<<<(G + 255) / 256, 256, 0, stream>>>(pooled, Wc1, bc1, Wc2, bc2,
                                                   (float*)d_out, G);
}